// Round 12
// baseline (237.204 us; speedup 1.0000x reference)
//
#include <hip/hip_runtime.h>
#include <math.h>

// TopKRouter: logits = rf @ gw^T, softmax, top-2, aux load-balance loss.
// rf: [16384, 4096] f32, gw: [64, 4096] f32.
// out (f32 flat): weights [0,32768) | indices-as-float [32768,65536) | aux [65536]
//
// R11: split-K MFMA GEMM with W RESIDENT IN LDS (staged once per block).
// Block = 128 rows x K-seg 256; 8 waves x 16 rows; W hi/lo frags (64 KB) are
// global_load_lds'ed once + one __syncthreads; hot loop is barrier-free:
// per K-step = 2 A-loads (4-deep reg ring, SBAR-pinned) + 8 ds_read_b128
// (conflict-free) + 12 MFMA (bf16-split 3-term). Partial logits (16 splits)
// go to ws; epilogue kernel reduces + softmax/top2/flags; cleanup recomputes
// near-ties in fp64 and computes aux.
// ws: [0,256) psum | [256,512) cnt | [512,516) flagcnt | [768,+32K) flaglist
//     | [1M, +1MB) W frag stream | [2M, +64MB) partial logits [16][16384][64].

typedef __attribute__((ext_vector_type(8))) short bf16x8;
typedef __attribute__((ext_vector_type(4))) float f32x4;

constexpr int B_ROWS  = 16384;
constexpr int D_DIM   = 4096;
constexpr int E_EXP   = 64;
constexpr int NTHR    = 512;
constexpr int TM      = 128;              // rows per gemm block
constexpr int KSEG    = 256;              // k-range per gemm block
constexpr int NSPLIT  = D_DIM / KSEG;     // 16
constexpr int NS      = KSEG / 32;        // 8 k-steps of 32
constexpr int FLAGCAP = 8192;
constexpr float GAPTHR = 1e-3f;

__device__ __forceinline__ float wave_max64(float v) {
#pragma unroll
  for (int m = 32; m >= 1; m >>= 1) v = fmaxf(v, __shfl_xor(v, m, 64));
  return v;
}
__device__ __forceinline__ float wave_sum64(float v) {
#pragma unroll
  for (int m = 32; m >= 1; m >>= 1) v += __shfl_xor(v, m, 64);
  return v;
}
// argmax over 64 lanes; ties -> smaller index (matches jax.lax.top_k)
__device__ __forceinline__ void wave_argmax64(float v, int i, float& mv, int& mi) {
#pragma unroll
  for (int m = 32; m >= 1; m >>= 1) {
    float ov = __shfl_xor(v, m, 64);
    int   oi = __shfl_xor(i, m, 64);
    if (ov > v || (ov == v && oi < i)) { v = ov; i = oi; }
  }
  mv = v; mi = i;
}

__device__ __forceinline__ void async_copy16(void* lds_dst, const void* g_src) {
  auto g = (const __attribute__((address_space(1))) char*)(g_src);
  auto l = (__attribute__((address_space(3))) char*)(lds_dst);
  __builtin_amdgcn_global_load_lds(g, l, 16, 0, 0);
}

// trunc-split 8 fp32 -> hi/lo bf16 frags (f = hi + rem exactly at bf16 precision)
__device__ __forceinline__ void split8(const f32x4 a, const f32x4 b, bf16x8& hi, bf16x8& lo) {
  float f[8] = {a[0], a[1], a[2], a[3], b[0], b[1], b[2], b[3]};
#pragma unroll
  for (int i = 0; i < 8; ++i) {
    unsigned int u = __float_as_uint(f[i]);
    hi[i] = (short)(u >> 16);
    float rem = f[i] - __uint_as_float(u & 0xffff0000u);
    lo[i] = (short)(__float_as_uint(rem) >> 16);
  }
}

// W pre-split: gw [64][4096] f32 -> frag stream [n=k/32][cb][h][lane][16B].
// B-frag (mfma_f32_16x16x32_bf16): lane l elem i <-> B[k=(l>>4)*8+i][col=l&15].
// Block 0 also zeroes the ws header (psum/cnt/flagcnt) - replaces memset launch.
__global__ __launch_bounds__(NTHR) void wsplit(const float* __restrict__ gw,
                                               char* __restrict__ wsW,
                                               unsigned int* __restrict__ hdr) {
  const int n = blockIdx.x;          // 128 k-steps
  const int t = threadIdx.x;
  if (n == 0 && t < 192) hdr[t] = 0u;
  const int lane = t & 63, h = (t >> 6) & 1, wc = t >> 7;
  const int col = wc * 16 + (lane & 15);
  const int k0  = n * 32 + (lane >> 4) * 8;
  const float* src = gw + (size_t)col * D_DIM + k0;
  union { unsigned short us[8]; uint4 v; } pk;
#pragma unroll
  for (int i = 0; i < 8; ++i) {
    float f = src[i];
    unsigned int u = __float_as_uint(f);
    if (h == 0) {
      pk.us[i] = (unsigned short)(u >> 16);
    } else {
      float rem = f - __uint_as_float(u & 0xffff0000u);
      pk.us[i] = (unsigned short)(__float_as_uint(rem) >> 16);
    }
  }
  *(uint4*)(wsW + (size_t)n * 8192 + (size_t)t * 16) = pk.v;
}

__global__ __launch_bounds__(NTHR) void gemm_partial(
    const float* __restrict__ rf, const char* __restrict__ wsW,
    float* __restrict__ part) {
  __shared__ char wlds[NS * 8192] __attribute__((aligned(16)));  // 64 KB

  const int t = threadIdx.x, lane = t & 63, wv = t >> 6;
  const int ks   = blockIdx.x >> 7;      // 16 k-segments
  const int rb   = blockIdx.x & 127;     // 128 row-blocks
  const int row0 = rb * TM;

  // stage this kseg's W frags (64 KB) once; layout identical to wsW chunk
  {
    const char* src = wsW + (size_t)ks * (NS * 8192);
#pragma unroll
    for (int i = 0; i < NS; ++i)
      async_copy16(wlds + i * 8192 + t * 16, src + i * 8192 + t * 16);
  }
  __syncthreads();  // compiler drains vmcnt here -> W visible to all waves

  // per-lane A fragment address: row = row0 + wv*16 + (lane&15),
  // k = ks*KSEG + (lane>>4)*8
  const float* aptr = rf + (size_t)(row0 + wv * 16 + (lane & 15)) * D_DIM
                         + ks * KSEG + (lane >> 4) * 8;

  f32x4 acc[4] = {{0.f,0.f,0.f,0.f},{0.f,0.f,0.f,0.f},{0.f,0.f,0.f,0.f},{0.f,0.f,0.f,0.f}};
  f32x4 a0[4], a1[4];   // 4-deep A ring (static indices under full unroll)

#define LDA(s, n) { a0[s] = *(const f32x4*)(aptr + (n) * 32); \
                    a1[s] = *(const f32x4*)(aptr + (n) * 32 + 4); }

  LDA(0, 0); LDA(1, 1); LDA(2, 2); LDA(3, 3);
  __builtin_amdgcn_sched_barrier(0);

#pragma unroll
  for (int n = 0; n < NS; ++n) {
    const int s = n & 3;
    bf16x8 ahi, alo;
    split8(a0[s], a1[s], ahi, alo);       // compiler waits this slot's loads
    if (n + 4 < NS) LDA(s, n + 4);        // refill slot (after its last read)
    __builtin_amdgcn_sched_barrier(0);    // pin refill issue before the MFMAs
    const char* wn = wlds + n * 8192 + lane * 16;
#pragma unroll
    for (int cb = 0; cb < 4; ++cb) {
      bf16x8 whi = *(const bf16x8*)(wn + cb * 2048);
      bf16x8 wlo = *(const bf16x8*)(wn + cb * 2048 + 1024);
      acc[cb] = __builtin_amdgcn_mfma_f32_16x16x32_bf16(ahi, whi, acc[cb], 0, 0, 0);
      acc[cb] = __builtin_amdgcn_mfma_f32_16x16x32_bf16(alo, whi, acc[cb], 0, 0, 0);
      acc[cb] = __builtin_amdgcn_mfma_f32_16x16x32_bf16(ahi, wlo, acc[cb], 0, 0, 0);
    }
    __builtin_amdgcn_sched_barrier(0);
  }
#undef LDA

  // store partial tile: D frag -> row = wv*16 + (lane>>4)*4 + j, col = cb*16 + (lane&15)
  const int colb = lane & 15;
  const int rowb = (lane >> 4) * 4;
  float* dst = part + ((size_t)ks * B_ROWS + row0 + wv * 16 + rowb) * E_EXP + colb;
#pragma unroll
  for (int cb = 0; cb < 4; ++cb)
#pragma unroll
    for (int j = 0; j < 4; ++j)
      dst[(size_t)j * E_EXP + cb * 16] = acc[cb][j];
}

// reduce the 16 partials, softmax, top-2 (+near-tie flagging), psum/cnt.
__global__ __launch_bounds__(NTHR) void epilogue(
    const float* __restrict__ part, float* __restrict__ out,
    float* __restrict__ psum, unsigned int* __restrict__ cnt,
    int* __restrict__ flagcnt, int* __restrict__ flaglist) {
  __shared__ float pcol[E_EXP];
  __shared__ unsigned int scnt[E_EXP];

  const int t = threadIdx.x, lane = t & 63, wv = t >> 6;
  const int row0 = blockIdx.x * 64;     // 64 rows/block, 256 blocks

  if (t < E_EXP) { scnt[t] = 0; pcol[t] = 0.f; }
  __syncthreads();

#pragma unroll
  for (int j = 0; j < 8; ++j) {
    const int row = row0 + wv * 8 + j;
    float lg = 0.f;
#pragma unroll
    for (int s = 0; s < NSPLIT; ++s)
      lg += part[((size_t)s * B_ROWS + row) * E_EXP + lane];

    const float m  = wave_max64(lg);
    const float p  = __expf(lg - m);
    const float ss = wave_sum64(p);
    atomicAdd(&pcol[lane], p / ss);

    float v1; int i1; wave_argmax64(lg, lane, v1, i1);
    const float lm1 = (lane == i1) ? -INFINITY : lg;
    float v2; int i2; wave_argmax64(lm1, lane, v2, i2);
    const float lm2 = (lane == i2) ? -INFINITY : lm1;
    float v3; int i3; wave_argmax64(lm2, lane, v3, i3);
    if (lane == 0) {
      const float ex = expf(v2 - v1);
      out[row * 2 + 0] = 1.f / (1.f + ex);
      out[row * 2 + 1] = ex / (1.f + ex);
      out[2 * B_ROWS + row * 2 + 0] = (float)i1;
      out[2 * B_ROWS + row * 2 + 1] = (float)i2;
      atomicAdd(&scnt[i1], 1u);
      atomicAdd(&scnt[i2], 1u);
      if (v1 - v2 < GAPTHR || v2 - v3 < GAPTHR) {
        int fi = atomicAdd(flagcnt, 1);
        if (fi < FLAGCAP) flaglist[fi] = row;
      }
    }
  }
  __syncthreads();
  if (t < E_EXP) {
    atomicAdd(&psum[t], pcol[t]);
    const unsigned int c = scnt[t];
    if (c) atomicAdd(&cnt[t], c);
  }
}

// exact fp64 recompute of flagged (near-tie) rows; block 0 also computes aux.
__global__ __launch_bounds__(256) void cleanup(
    const float* __restrict__ rf, const float* __restrict__ gw,
    const int* __restrict__ flagcnt, const int* __restrict__ flaglist,
    const float* __restrict__ psum, const unsigned int* __restrict__ cnt,
    float* __restrict__ out) {
  __shared__ double sm[256];
  const int t = threadIdx.x;
  if (blockIdx.x == 0 && t < 64) {
    const float f = (float)cnt[t] / (float)(B_ROWS * 2);
    const float P = psum[t] / (float)B_ROWS;
    float v = wave_sum64(f * P);
    if (t == 0) out[4 * B_ROWS] = (float)E_EXP * v;
  }
  const int nf = min(*flagcnt, FLAGCAP);
  for (int fi = blockIdx.x; fi < nf; fi += gridDim.x) {
    const int row = flaglist[fi];
    const int e = t & 63, seg = t >> 6;
    const float* a = rf + (size_t)row * D_DIM + seg * 1024;
    const float* w = gw + (size_t)e * D_DIM + seg * 1024;
    double p0 = 0.0, p1 = 0.0, p2 = 0.0, p3 = 0.0;
    for (int k = 0; k < 1024; k += 4) {
      p0 = fma((double)a[k + 0], (double)w[k + 0], p0);
      p1 = fma((double)a[k + 1], (double)w[k + 1], p1);
      p2 = fma((double)a[k + 2], (double)w[k + 2], p2);
      p3 = fma((double)a[k + 3], (double)w[k + 3], p3);
    }
    sm[t] = (p0 + p1) + (p2 + p3);
    __syncthreads();
    if (t < 64) {
      const double l = sm[t] + sm[64 + t] + sm[128 + t] + sm[192 + t];
      double v = l; int ii = t;
#pragma unroll
      for (int m = 32; m >= 1; m >>= 1) {
        double ov = __shfl_xor(v, m, 64); int oi = __shfl_xor(ii, m, 64);
        if (ov > v || (ov == v && oi < ii)) { v = ov; ii = oi; }
      }
      const double v1 = v; const int i1 = ii;
      const double lm = (t == i1) ? -1e300 : l;
      v = lm; ii = t;
#pragma unroll
      for (int m = 32; m >= 1; m >>= 1) {
        double ov = __shfl_xor(v, m, 64); int oi = __shfl_xor(ii, m, 64);
        if (ov > v || (ov == v && oi < ii)) { v = ov; ii = oi; }
      }
      const double v2 = v; const int i2 = ii;
      if (t == 0) {
        const double ex = exp(v2 - v1);
        out[row * 2 + 0] = (float)(1.0 / (1.0 + ex));
        out[row * 2 + 1] = (float)(ex / (1.0 + ex));
        out[2 * B_ROWS + row * 2 + 0] = (float)i1;
        out[2 * B_ROWS + row * 2 + 1] = (float)i2;
      }
    }
    __syncthreads();
  }
}

extern "C" void kernel_launch(void* const* d_in, const int* in_sizes, int n_in,
                              void* d_out, int out_size, void* d_ws, size_t ws_size,
                              hipStream_t stream) {
  const float* rf = (const float*)d_in[0];
  const float* gw = (const float*)d_in[1];
  float* out = (float*)d_out;
  float* psum = (float*)d_ws;
  unsigned int* cnt = (unsigned int*)((char*)d_ws + 256);
  int* flagcnt = (int*)((char*)d_ws + 512);
  int* flaglist = (int*)((char*)d_ws + 768);
  char* wsW = (char*)d_ws + (1u << 20);
  float* part = (float*)((char*)d_ws + (2u << 20));

  wsplit<<<D_DIM / 32, NTHR, 0, stream>>>(gw, wsW, (unsigned int*)d_ws);
  gemm_partial<<<NSPLIT * (B_ROWS / TM), NTHR, 0, stream>>>(rf, wsW, part);
  epilogue<<<B_ROWS / 64, NTHR, 0, stream>>>(part, out, psum, cnt, flagcnt, flaglist);
  cleanup<<<64, 256, 0, stream>>>(rf, gw, flagcnt, flaglist, psum, cnt, out);
}

// Round 13
// 204.392 us; speedup vs baseline: 1.1605x; 1.1605x over previous
//
#include <hip/hip_runtime.h>
#include <math.h>

// TopKRouter: logits = rf @ gw^T, softmax, top-2, aux load-balance loss.
// rf: [16384, 4096] f32, gw: [64, 4096] f32.
// out (f32 flat): weights [0,32768) | indices-as-float [32768,65536) | aux [65536]
//
// R12: m97-regime GEMM. Block = 128 rows x KSEG 512, 256 thr (4 waves),
// 48 KB LDS (A dbuf 2x16K + W-frag dbuf 2x8K) -> 3 blocks/CU. Staging via
// global_load_lds (A source pre-swizzled slot^=row&7, LDS linear), counted
// s_waitcnt vmcnt(6) + raw s_barrier (tile n+1 always in flight), bf16-split
// 3-term MFMA. Partials [8][16384][64] -> epilogue reduces + softmax/top2;
// cleanup recomputes near-ties in fp64 + aux.
// ws: [0,256) psum | [256,512) cnt | [512,516) flagcnt | [768,+32K) flaglist
//     | [1M, +1MB) W frag stream | [2M, +32MB) partials.

typedef __attribute__((ext_vector_type(8))) short bf16x8;
typedef __attribute__((ext_vector_type(4))) float f32x4;

constexpr int B_ROWS  = 16384;
constexpr int D_DIM   = 4096;
constexpr int E_EXP   = 64;
constexpr int NTHR    = 512;              // wsplit/epilogue threads
constexpr int GTHR    = 256;              // gemm threads (4 waves)
constexpr int TM      = 128;              // rows per gemm block
constexpr int KSEG    = 512;              // k-range per gemm block
constexpr int NSPLIT  = D_DIM / KSEG;     // 8
constexpr int NS      = KSEG / 32;        // 16 k-steps
constexpr int FLAGCAP = 8192;
constexpr float GAPTHR = 1e-3f;

__device__ __forceinline__ float wave_max64(float v) {
#pragma unroll
  for (int m = 32; m >= 1; m >>= 1) v = fmaxf(v, __shfl_xor(v, m, 64));
  return v;
}
__device__ __forceinline__ float wave_sum64(float v) {
#pragma unroll
  for (int m = 32; m >= 1; m >>= 1) v += __shfl_xor(v, m, 64);
  return v;
}
// argmax over 64 lanes; ties -> smaller index (matches jax.lax.top_k)
__device__ __forceinline__ void wave_argmax64(float v, int i, float& mv, int& mi) {
#pragma unroll
  for (int m = 32; m >= 1; m >>= 1) {
    float ov = __shfl_xor(v, m, 64);
    int   oi = __shfl_xor(i, m, 64);
    if (ov > v || (ov == v && oi < i)) { v = ov; i = oi; }
  }
  mv = v; mi = i;
}

__device__ __forceinline__ void async_copy16(void* lds_dst, const void* g_src) {
  auto g = (const __attribute__((address_space(1))) char*)(g_src);
  auto l = (__attribute__((address_space(3))) char*)(lds_dst);
  __builtin_amdgcn_global_load_lds(g, l, 16, 0, 0);
}

// trunc-split 8 fp32 -> hi/lo bf16 frags (f = hi + rem exactly at bf16 precision)
__device__ __forceinline__ void split8(const f32x4 a, const f32x4 b, bf16x8& hi, bf16x8& lo) {
  float f[8] = {a[0], a[1], a[2], a[3], b[0], b[1], b[2], b[3]};
#pragma unroll
  for (int i = 0; i < 8; ++i) {
    unsigned int u = __float_as_uint(f[i]);
    hi[i] = (short)(u >> 16);
    float rem = f[i] - __uint_as_float(u & 0xffff0000u);
    lo[i] = (short)(__float_as_uint(rem) >> 16);
  }
}

// W pre-split: gw [64][4096] f32 -> frag stream [n=k/32][cb][h][lane][16B].
// B-frag (mfma_f32_16x16x32_bf16): lane l elem i <-> B[k=(l>>4)*8+i][col=l&15].
// Block 0 also zeroes the ws header (psum/cnt/flagcnt).
__global__ __launch_bounds__(NTHR) void wsplit(const float* __restrict__ gw,
                                               char* __restrict__ wsW,
                                               unsigned int* __restrict__ hdr) {
  const int n = blockIdx.x;          // 128 k-steps
  const int t = threadIdx.x;
  if (n == 0 && t < 192) hdr[t] = 0u;
  const int lane = t & 63, h = (t >> 6) & 1, wc = t >> 7;
  const int col = wc * 16 + (lane & 15);
  const int k0  = n * 32 + (lane >> 4) * 8;
  const float* src = gw + (size_t)col * D_DIM + k0;
  union { unsigned short us[8]; uint4 v; } pk;
#pragma unroll
  for (int i = 0; i < 8; ++i) {
    float f = src[i];
    unsigned int u = __float_as_uint(f);
    if (h == 0) {
      pk.us[i] = (unsigned short)(u >> 16);
    } else {
      float rem = f - __uint_as_float(u & 0xffff0000u);
      pk.us[i] = (unsigned short)(__float_as_uint(rem) >> 16);
    }
  }
  *(uint4*)(wsW + (size_t)n * 8192 + (size_t)t * 16) = pk.v;
}

__global__ __launch_bounds__(GTHR) void gemm_partial(
    const float* __restrict__ rf, const char* __restrict__ wsW,
    float* __restrict__ part) {
  // A0 @0, A1 @16K, W0 @32K, W1 @40K  (48 KB total -> 3 blocks/CU)
  __shared__ char lds[49152] __attribute__((aligned(16)));

  const int t = threadIdx.x, lane = t & 63, wv = t >> 6;
  const int rb = blockIdx.x & 127, ks = blockIdx.x >> 7;
  const int row0 = rb * TM;

  // staging: A tile [128 rows][8 slots of 16B]; LDS linear, source slot
  // pre-swizzled (s_glob = s_lds ^ (row&7)) for conflict-free frag reads.
  int goffA[4];                         // float offsets, + n*32 per k-step
#pragma unroll
  for (int j = 0; j < 4; ++j) {
    const int q = j * GTHR + t;
    const int row = q >> 3, sl = q & 7;
    goffA[j] = (row0 + row) * D_DIM + ks * KSEG + ((sl ^ (row & 7)) << 2);
  }
  const char* wsrc = wsW + (size_t)(ks * NS) * 8192;

  // compute-side A frag read offsets (logical slot s -> LDS slot s^(row&7))
  const int s0 = (lane >> 4) * 2;
  const int rr0 = wv * 32 + (lane & 15);
  const int rr1 = rr0 + 16;
  const int a00 = rr0 * 128 + ((s0 ^ (rr0 & 7)) << 4);
  const int a01 = rr0 * 128 + (((s0 + 1) ^ (rr0 & 7)) << 4);
  const int a10 = rr1 * 128 + ((s0 ^ (rr1 & 7)) << 4);
  const int a11 = rr1 * 128 + (((s0 + 1) ^ (rr1 & 7)) << 4);

  f32x4 acc0[4] = {{0.f,0.f,0.f,0.f},{0.f,0.f,0.f,0.f},{0.f,0.f,0.f,0.f},{0.f,0.f,0.f,0.f}};
  f32x4 acc1[4] = {{0.f,0.f,0.f,0.f},{0.f,0.f,0.f,0.f},{0.f,0.f,0.f,0.f},{0.f,0.f,0.f,0.f}};

#define ISSUE(n)                                                             \
  {                                                                          \
    char* ab_ = lds + ((n) & 1) * 16384;                                     \
    char* wb_ = lds + 32768 + ((n) & 1) * 8192;                              \
    _Pragma("unroll") for (int j = 0; j < 4; ++j)                            \
      async_copy16(ab_ + (j * GTHR + t) * 16, rf + goffA[j] + (n) * 32);     \
    async_copy16(wb_ + t * 16, wsrc + (size_t)(n) * 8192 + t * 16);          \
    async_copy16(wb_ + (GTHR + t) * 16,                                      \
                 wsrc + (size_t)(n) * 8192 + (GTHR + t) * 16);               \
  }

  ISSUE(0);
#pragma unroll 2
  for (int n = 0; n < NS; ++n) {
    if (n + 1 < NS) {
      ISSUE(n + 1);                                    // tile n+1 in flight
      asm volatile("s_waitcnt vmcnt(6)" ::: "memory"); // tile n resident (mine)
    } else {
      asm volatile("s_waitcnt vmcnt(0)" ::: "memory");
    }
    __builtin_amdgcn_s_barrier();                      // tile n resident (all)

    const char* ab = lds + (n & 1) * 16384;
    const char* wb = lds + 32768 + (n & 1) * 8192 + lane * 16;
    const f32x4 fl0 = *(const f32x4*)(ab + a00);
    const f32x4 fh0 = *(const f32x4*)(ab + a01);
    const f32x4 fl1 = *(const f32x4*)(ab + a10);
    const f32x4 fh1 = *(const f32x4*)(ab + a11);
    bf16x8 ahi0, alo0, ahi1, alo1;
    split8(fl0, fh0, ahi0, alo0);
    split8(fl1, fh1, ahi1, alo1);
#pragma unroll
    for (int cb = 0; cb < 4; ++cb) {
      const bf16x8 whi = *(const bf16x8*)(wb + cb * 2048);
      const bf16x8 wlo = *(const bf16x8*)(wb + cb * 2048 + 1024);
      acc0[cb] = __builtin_amdgcn_mfma_f32_16x16x32_bf16(ahi0, whi, acc0[cb], 0, 0, 0);
      acc0[cb] = __builtin_amdgcn_mfma_f32_16x16x32_bf16(alo0, whi, acc0[cb], 0, 0, 0);
      acc0[cb] = __builtin_amdgcn_mfma_f32_16x16x32_bf16(ahi0, wlo, acc0[cb], 0, 0, 0);
      acc1[cb] = __builtin_amdgcn_mfma_f32_16x16x32_bf16(ahi1, whi, acc1[cb], 0, 0, 0);
      acc1[cb] = __builtin_amdgcn_mfma_f32_16x16x32_bf16(alo1, whi, acc1[cb], 0, 0, 0);
      acc1[cb] = __builtin_amdgcn_mfma_f32_16x16x32_bf16(ahi1, wlo, acc1[cb], 0, 0, 0);
    }
    __builtin_amdgcn_s_barrier();                      // buf (n&1) free
  }
#undef ISSUE

  // store partials: D frag -> row = (lane>>4)*4+j, col = cb*16+(lane&15)
  const int colb = lane & 15;
  const int rowb = (lane >> 4) * 4;
  float* dst = part + ((size_t)ks * B_ROWS + row0 + wv * 32 + rowb) * E_EXP + colb;
#pragma unroll
  for (int cb = 0; cb < 4; ++cb)
#pragma unroll
    for (int j = 0; j < 4; ++j) {
      dst[(size_t)j * E_EXP + cb * 16] = acc0[cb][j];
      dst[(size_t)(j + 16) * E_EXP + cb * 16] = acc1[cb][j];
    }
}

// reduce the 8 partials, softmax, top-2 (+near-tie flagging), psum/cnt.
__global__ __launch_bounds__(NTHR) void epilogue(
    const float* __restrict__ part, float* __restrict__ out,
    float* __restrict__ psum, unsigned int* __restrict__ cnt,
    int* __restrict__ flagcnt, int* __restrict__ flaglist) {
  __shared__ float pcol[E_EXP];
  __shared__ unsigned int scnt[E_EXP];

  const int t = threadIdx.x, lane = t & 63, wv = t >> 6;
  const int row0 = blockIdx.x * 64;     // 64 rows/block, 256 blocks

  if (t < E_EXP) { scnt[t] = 0; pcol[t] = 0.f; }
  __syncthreads();

#pragma unroll
  for (int j = 0; j < 8; ++j) {
    const int row = row0 + wv * 8 + j;
    float lg = 0.f;
#pragma unroll
    for (int s = 0; s < NSPLIT; ++s)
      lg += part[((size_t)s * B_ROWS + row) * E_EXP + lane];

    const float m  = wave_max64(lg);
    const float p  = __expf(lg - m);
    const float ss = wave_sum64(p);
    atomicAdd(&pcol[lane], p / ss);

    float v1; int i1; wave_argmax64(lg, lane, v1, i1);
    const float lm1 = (lane == i1) ? -INFINITY : lg;
    float v2; int i2; wave_argmax64(lm1, lane, v2, i2);
    const float lm2 = (lane == i2) ? -INFINITY : lm1;
    float v3; int i3; wave_argmax64(lm2, lane, v3, i3);
    if (lane == 0) {
      const float ex = expf(v2 - v1);
      out[row * 2 + 0] = 1.f / (1.f + ex);
      out[row * 2 + 1] = ex / (1.f + ex);
      out[2 * B_ROWS + row * 2 + 0] = (float)i1;
      out[2 * B_ROWS + row * 2 + 1] = (float)i2;
      atomicAdd(&scnt[i1], 1u);
      atomicAdd(&scnt[i2], 1u);
      if (v1 - v2 < GAPTHR || v2 - v3 < GAPTHR) {
        int fi = atomicAdd(flagcnt, 1);
        if (fi < FLAGCAP) flaglist[fi] = row;
      }
    }
  }
  __syncthreads();
  if (t < E_EXP) {
    atomicAdd(&psum[t], pcol[t]);
    const unsigned int c = scnt[t];
    if (c) atomicAdd(&cnt[t], c);
  }
}

// exact fp64 recompute of flagged (near-tie) rows; block 0 also computes aux.
__global__ __launch_bounds__(256) void cleanup(
    const float* __restrict__ rf, const float* __restrict__ gw,
    const int* __restrict__ flagcnt, const int* __restrict__ flaglist,
    const float* __restrict__ psum, const unsigned int* __restrict__ cnt,
    float* __restrict__ out) {
  __shared__ double sm[256];
  const int t = threadIdx.x;
  if (blockIdx.x == 0 && t < 64) {
    const float f = (float)cnt[t] / (float)(B_ROWS * 2);
    const float P = psum[t] / (float)B_ROWS;
    float v = wave_sum64(f * P);
    if (t == 0) out[4 * B_ROWS] = (float)E_EXP * v;
  }
  const int nf = min(*flagcnt, FLAGCAP);
  for (int fi = blockIdx.x; fi < nf; fi += gridDim.x) {
    const int row = flaglist[fi];
    const int e = t & 63, seg = t >> 6;
    const float* a = rf + (size_t)row * D_DIM + seg * 1024;
    const float* w = gw + (size_t)e * D_DIM + seg * 1024;
    double p0 = 0.0, p1 = 0.0, p2 = 0.0, p3 = 0.0;
    for (int k = 0; k < 1024; k += 4) {
      p0 = fma((double)a[k + 0], (double)w[k + 0], p0);
      p1 = fma((double)a[k + 1], (double)w[k + 1], p1);
      p2 = fma((double)a[k + 2], (double)w[k + 2], p2);
      p3 = fma((double)a[k + 3], (double)w[k + 3], p3);
    }
    sm[t] = (p0 + p1) + (p2 + p3);
    __syncthreads();
    if (t < 64) {
      const double l = sm[t] + sm[64 + t] + sm[128 + t] + sm[192 + t];
      double v = l; int ii = t;
#pragma unroll
      for (int m = 32; m >= 1; m >>= 1) {
        double ov = __shfl_xor(v, m, 64); int oi = __shfl_xor(ii, m, 64);
        if (ov > v || (ov == v && oi < ii)) { v = ov; ii = oi; }
      }
      const double v1 = v; const int i1 = ii;
      const double lm = (t == i1) ? -1e300 : l;
      v = lm; ii = t;
#pragma unroll
      for (int m = 32; m >= 1; m >>= 1) {
        double ov = __shfl_xor(v, m, 64); int oi = __shfl_xor(ii, m, 64);
        if (ov > v || (ov == v && oi < ii)) { v = ov; ii = oi; }
      }
      const double v2 = v; const int i2 = ii;
      if (t == 0) {
        const double ex = exp(v2 - v1);
        out[row * 2 + 0] = (float)(1.0 / (1.0 + ex));
        out[row * 2 + 1] = (float)(ex / (1.0 + ex));
        out[2 * B_ROWS + row * 2 + 0] = (float)i1;
        out[2 * B_ROWS + row * 2 + 1] = (float)i2;
      }
    }
    __syncthreads();
  }
}

extern "C" void kernel_launch(void* const* d_in, const int* in_sizes, int n_in,
                              void* d_out, int out_size, void* d_ws, size_t ws_size,
                              hipStream_t stream) {
  const float* rf = (const float*)d_in[0];
  const float* gw = (const float*)d_in[1];
  float* out = (float*)d_out;
  float* psum = (float*)d_ws;
  unsigned int* cnt = (unsigned int*)((char*)d_ws + 256);
  int* flagcnt = (int*)((char*)d_ws + 512);
  int* flaglist = (int*)((char*)d_ws + 768);
  char* wsW = (char*)d_ws + (1u << 20);
  float* part = (float*)((char*)d_ws + (2u << 20));

  wsplit<<<D_DIM / 32, NTHR, 0, stream>>>(gw, wsW, (unsigned int*)d_ws);
  gemm_partial<<<NSPLIT * (B_ROWS / TM), GTHR, 0, stream>>>(rf, wsW, part);
  epilogue<<<B_ROWS / 64, NTHR, 0, stream>>>(part, out, psum, cnt, flagcnt, flaglist);
  cleanup<<<64, 256, 0, stream>>>(rf, gw, flagcnt, flaglist, psum, cnt, out);
}